// Round 1
// baseline (97.516 us; speedup 1.0000x reference)
//
#include <hip/hip_runtime.h>
#include <stdint.h>

// Problem constants (match reference)
#define Bdim 64
#define Tdim 1024
#define Edim 128
#define Cdim 5
#define Fdim 64
#define Hpad 2      // C/2
#define Kdim (Cdim * Edim)   // 640

// Tile geometry (TTILE=64 measured sweet spot in prior session: 32->90.1, 64->87.8, 128->97.4)
#define TTILE 64                 // t-positions per workgroup
#define XROWS (TTILE + Cdim - 1) // 68 rows: t0-2 .. t0+65
#define LDSTR (Edim + 8)         // 136 shorts/row

typedef __attribute__((ext_vector_type(8))) short short8;     // 8 bf16 = 4 VGPRs (MFMA frag)
typedef __attribute__((ext_vector_type(4))) float float4v;
typedef __attribute__((ext_vector_type(4))) unsigned short ushort4v;

__device__ __forceinline__ unsigned short f2bf(float f) {
    // round-to-nearest-even fp32 -> bf16 (inputs finite randn; no NaN path needed)
    union { float f; uint32_t u; } v; v.f = f;
    uint32_t u = v.u;
    u += 0x7fffu + ((u >> 16) & 1u);
    return (unsigned short)(u >> 16);
}

__device__ __forceinline__ short8 cvt8(float4v a, float4v b) {
    union { unsigned short s[8]; short8 v; } u;
    u.s[0] = f2bf(a.x); u.s[1] = f2bf(a.y); u.s[2] = f2bf(a.z); u.s[3] = f2bf(a.w);
    u.s[4] = f2bf(b.x); u.s[5] = f2bf(b.y); u.s[6] = f2bf(b.z); u.s[7] = f2bf(b.w);
    return u.v;
}

// ---- Single kernel, NO WORKSPACE. R0 theory: the 256 MiB ws-poison fill
// (__amd_rocclr_fillBufferAligned, 45.6us, 51% of dur_us) sits in the timed
// region because we touch d_ws. W (160 KB fp32, L2-hot) is now loaded and
// converted to bf16 B-fragments in-register, per tap, software-pipelined.
// Fragment mapping preserved exactly from the verified swizzled-Wbf version:
//   B-frag elem j = bf16(W[f = wave*16+m16][k = c*128 + kk*32 + quad*8 + j])
__global__ __launch_bounds__(256, 4)
void qa_cnn_main(const float* __restrict__ x, const float* __restrict__ W,
                 const float* __restrict__ bias, float* __restrict__ out) {
    __shared__ __align__(16) unsigned short sX[XROWS * LDSTR]; // 18,496 B

    const int tid = threadIdx.x;
    const int tt  = blockIdx.x;   // 0..15
    const int b   = blockIdx.y;   // 0..63
    const int t0  = tt * TTILE;

    const int wave = tid >> 6;     // 0..3 -> this wave's 16-f slice
    const int lane = tid & 63;
    const int m16  = lane & 15;
    const int quad = lane >> 4;

    // Per-lane W base: row f = wave*16 + m16, k-octet offset quad*8
    const float* wbase = W + (size_t)(wave * 16 + m16) * Kdim + quad * 8;

    // ---- Stage x window: issue ALL 9 global loads first (batched -> MLP hides
    // HBM latency across the wave), then convert+store to LDS.
    float4v xv[9];
    #pragma unroll
    for (int i = 0; i < 9; ++i) {
        const int idx = tid + i * 256;            // 2176 float4 slots total
        float4v v = {0.f, 0.f, 0.f, 0.f};
        if (idx < XROWS * (Edim / 4)) {           // only i==8 is partial (tid<128)
            const int row = idx >> 5;
            const int c4  = idx & 31;
            const int gt  = t0 - Hpad + row;
            if (gt >= 0 && gt < Tdim)
                v = *(const float4v*)(x + ((size_t)b * Tdim + gt) * Edim + c4 * 4);
        }
        xv[i] = v;
    }

    // Prefetch tap-0 W (fp32, L2-hot) so its latency overlaps the LDS staging.
    float4v w0[8];
    #pragma unroll
    for (int kk = 0; kk < 4; ++kk) {
        w0[kk * 2]     = *(const float4v*)(wbase + kk * 32);
        w0[kk * 2 + 1] = *(const float4v*)(wbase + kk * 32 + 4);
    }

    #pragma unroll
    for (int i = 0; i < 9; ++i) {
        const int idx = tid + i * 256;
        if (idx < XROWS * (Edim / 4)) {
            const int row = idx >> 5;
            const int c4  = idx & 31;
            ushort4v o = { f2bf(xv[i].x), f2bf(xv[i].y), f2bf(xv[i].z), f2bf(xv[i].w) };
            *(ushort4v*)&sX[row * LDSTR + c4 * 4] = o;
        }
    }

    float4v acc[4];
    #pragma unroll
    for (int mt = 0; mt < 4; ++mt) acc[mt] = (float4v){0.f, 0.f, 0.f, 0.f};

    __syncthreads();   // the only barrier

    short8 bfrag[4];
    #pragma unroll
    for (int kk = 0; kk < 4; ++kk) bfrag[kk] = cvt8(w0[kk * 2], w0[kk * 2 + 1]);

    #pragma unroll
    for (int c = 0; c < Cdim; ++c) {
        // Software-pipeline: prefetch next tap's W slice during this tap's MFMAs.
        float4v wn[8];
        if (c + 1 < Cdim) {
            #pragma unroll
            for (int kk = 0; kk < 4; ++kk) {
                wn[kk * 2]     = *(const float4v*)(wbase + (c + 1) * Edim + kk * 32);
                wn[kk * 2 + 1] = *(const float4v*)(wbase + (c + 1) * Edim + kk * 32 + 4);
            }
        }

        #pragma unroll
        for (int kk = 0; kk < 4; ++kk) {
            const int kcol = kk * 32 + quad * 8;
            #pragma unroll
            for (int mt = 0; mt < 4; ++mt) {
                // A[m = m16][k], row in sX shifted by tap c
                const short8 a = *(const short8*)&sX[(c + mt * 16 + m16) * LDSTR + kcol];
                acc[mt] = __builtin_amdgcn_mfma_f32_16x16x32_bf16(a, bfrag[kk], acc[mt], 0, 0, 0);
            }
        }

        if (c + 1 < Cdim) {
            #pragma unroll
            for (int kk = 0; kk < 4; ++kk) bfrag[kk] = cvt8(wn[kk * 2], wn[kk * 2 + 1]);
        }
    }

    // Epilogue: D col(n)=lane&15 -> f, row(m)=quad*4+reg -> t. 4 consecutive t/lane.
    const int f  = wave * 16 + m16;
    const float bv = bias[f];
    float* orow = out + ((size_t)b * Fdim + f) * Tdim + t0 + quad * 4;
    #pragma unroll
    for (int mt = 0; mt < 4; ++mt) {
        float4v v = acc[mt];
        v.x += bv; v.y += bv; v.z += bv; v.w += bv;
        *(float4v*)(orow + mt * 16) = v;
    }
}

extern "C" void kernel_launch(void* const* d_in, const int* in_sizes, int n_in,
                              void* d_out, int out_size, void* d_ws, size_t ws_size,
                              hipStream_t stream) {
    (void)in_sizes; (void)n_in; (void)out_size; (void)d_ws; (void)ws_size;
    const float* x    = (const float*)d_in[0];   // [B, T, E]
    const float* W    = (const float*)d_in[1];   // [F, C*E]
    const float* bias = (const float*)d_in[2];   // [F]
    float* out = (float*)d_out;                  // [B, F, T]

    // Workspace deliberately untouched (R0 experiment: does the 45.6us
    // 256 MiB ws-poison fill leave the timed region?)
    qa_cnn_main<<<dim3(Tdim / TTILE, Bdim), dim3(256), 0, stream>>>(x, W, bias, out);
}